// Round 1
// baseline (517.441 us; speedup 1.0000x reference)
//
#include <hip/hip_runtime.h>
#include <hip/hip_bf16.h>

// GraphSAGE: 3 layers of (gather -> segment-mean -> h@Ws + agg@Wn + b (+ReLU))
// N=50000 nodes, E=800000 edges, dims 128->128->128->64, all fp32.
//
// Plan: build CSR once per launch (deg count -> scan -> counting sort fill),
// then per layer: per-node register aggregation (no float atomics) + tiled
// fp32 GEMM with K=256 (concat [h, h_neigh] x [Ws; Wn]).

#define NFEAT 128

// ---------------- CSR build ----------------

__global__ void k_deg(const int* __restrict__ dst, int* __restrict__ deg, int E) {
    int e = blockIdx.x * 256 + threadIdx.x;
    if (e < E) atomicAdd(&deg[dst[e]], 1);
}

__global__ void k_scan1(const int* __restrict__ deg, int* __restrict__ ptrA,
                        int* __restrict__ partials, int NN) {
    __shared__ int sh[256];
    int t = threadIdx.x;
    int i = blockIdx.x * 256 + t;
    int v = (i < NN) ? deg[i] : 0;
    sh[t] = v;
    __syncthreads();
#pragma unroll
    for (int off = 1; off < 256; off <<= 1) {
        int x = (t >= off) ? sh[t - off] : 0;
        __syncthreads();
        sh[t] += x;
        __syncthreads();
    }
    if (i < NN) ptrA[i] = sh[t] - v;           // block-local exclusive
    if (t == 255) partials[blockIdx.x] = sh[255];
}

__global__ void k_scan2(int* __restrict__ partials, int nb) {
    __shared__ int sh[256];
    int t = threadIdx.x;
    int v = (t < nb) ? partials[t] : 0;
    sh[t] = v;
    __syncthreads();
#pragma unroll
    for (int off = 1; off < 256; off <<= 1) {
        int x = (t >= off) ? sh[t - off] : 0;
        __syncthreads();
        sh[t] += x;
        __syncthreads();
    }
    if (t < nb) partials[t] = sh[t] - v;       // exclusive block prefix
}

__global__ void k_scan3(int* __restrict__ ptrA, const int* __restrict__ partials,
                        int NN, int E) {
    int i = blockIdx.x * 256 + threadIdx.x;
    if (i < NN) ptrA[i] += partials[blockIdx.x];
    if (i == 0) ptrA[NN] = E;
}

__global__ void k_fill(const int* __restrict__ src, const int* __restrict__ dst,
                       const int* __restrict__ ptrA, int* __restrict__ fill,
                       int* __restrict__ csr, int E) {
    int e = blockIdx.x * 256 + threadIdx.x;
    if (e < E) {
        int d = dst[e];
        int pos = ptrA[d] + atomicAdd(&fill[d], 1);
        csr[pos] = src[e];
    }
}

// ---------------- mean aggregation (one node per 128-thread block) ----------------

__global__ __launch_bounds__(128) void k_agg(const float* __restrict__ H,
                                             const int* __restrict__ ptrA,
                                             const int* __restrict__ csr,
                                             float* __restrict__ AGG) {
    int n = blockIdx.x;
    int t = threadIdx.x;                       // feature index 0..127
    int beg = ptrA[n], end = ptrA[n + 1];
    float acc = 0.f;
    int e = beg;
    for (; e + 4 <= end; e += 4) {
        int s0 = csr[e + 0], s1 = csr[e + 1], s2 = csr[e + 2], s3 = csr[e + 3];
        acc += H[(size_t)s0 * NFEAT + t];
        acc += H[(size_t)s1 * NFEAT + t];
        acc += H[(size_t)s2 * NFEAT + t];
        acc += H[(size_t)s3 * NFEAT + t];
    }
    for (; e < end; ++e) acc += H[(size_t)csr[e] * NFEAT + t];
    int d = end - beg;
    float inv = (d > 0) ? 1.0f / (float)d : 0.0f;   // max(deg,1); acc==0 when d==0
    AGG[(size_t)n * NFEAT + t] = acc * inv;
}

// ---------------- fused GEMM: C = H@Ws + AGG@Wn + b (+ReLU) ----------------
// Logical K = 256: k<128 reads H/Ws, k>=128 reads AGG/Wn. BN = full output
// width so layer-1 can run in-place (each block only reads rows it writes).

template <int BN>
__global__ __launch_bounds__(256) void gemm_sage(
    const float* __restrict__ H, const float* __restrict__ AGG,
    const float* __restrict__ Ws, const float* __restrict__ Wn,
    const float* __restrict__ bias, float* __restrict__ C, int M, int relu) {
    constexpr int BM = 64, BK = 16;
    constexpr int TN = BN / 16;   // 8 (BN=128) or 4 (BN=64)
    constexpr int TM = 4;
    __shared__ float As[BK][BM + 4];   // [k][m], padded vs bank conflicts
    __shared__ float Bs[BK][BN];

    int t = threadIdx.x;
    int tx = t & 15, ty = t >> 4;
    int m0 = blockIdx.x * BM;

    float acc[TM][TN] = {};

    for (int kb = 0; kb < 256; kb += BK) {
        const float* Asrc = (kb < 128) ? H : AGG;
        const float* Bsrc = (kb < 128) ? Ws : Wn;
        int kOff = (kb < 128) ? kb : (kb - 128);

        // A tile: BM x BK
#pragma unroll
        for (int i = 0; i < (BM * BK) / 256; ++i) {
            int idx = t + i * 256;
            int r = idx >> 4, c = idx & 15;
            float v = 0.f;
            if (m0 + r < M) v = Asrc[(size_t)(m0 + r) * NFEAT + kOff + c];
            As[c][r] = v;
        }
        // B tile: BK x BN (row-major weights, coalesced)
#pragma unroll
        for (int i = 0; i < (BK * BN) / 256; ++i) {
            int idx = t + i * 256;
            int r = idx / BN, c = idx % BN;
            Bs[r][c] = Bsrc[(size_t)(kOff + r) * BN + c];
        }
        __syncthreads();

#pragma unroll
        for (int kk = 0; kk < BK; ++kk) {
            float a[TM], b[TN];
#pragma unroll
            for (int i = 0; i < TM; ++i) a[i] = As[kk][ty * TM + i];
#pragma unroll
            for (int j = 0; j < TN; ++j) b[j] = Bs[kk][tx + 16 * j];
#pragma unroll
            for (int i = 0; i < TM; ++i)
#pragma unroll
                for (int j = 0; j < TN; ++j) acc[i][j] += a[i] * b[j];
        }
        __syncthreads();
    }

#pragma unroll
    for (int i = 0; i < TM; ++i) {
        int m = m0 + ty * TM + i;
        if (m < M) {
#pragma unroll
            for (int j = 0; j < TN; ++j) {
                int n = tx + 16 * j;
                float v = acc[i][j] + bias[n];
                if (relu) v = fmaxf(v, 0.f);
                C[(size_t)m * BN + n] = v;
            }
        }
    }
}

// ---------------- launch ----------------

static inline size_t align_up(size_t x) { return (x + 255) & ~(size_t)255; }

extern "C" void kernel_launch(void* const* d_in, const int* in_sizes, int n_in,
                              void* d_out, int out_size, void* d_ws, size_t ws_size,
                              hipStream_t stream) {
    const float* x   = (const float*)d_in[0];
    const int*   src = (const int*)d_in[1];
    const int*   dst = (const int*)d_in[2];
    const float* Ws0 = (const float*)d_in[3];
    const float* Wn0 = (const float*)d_in[4];
    const float* b0  = (const float*)d_in[5];
    const float* Ws1 = (const float*)d_in[6];
    const float* Wn1 = (const float*)d_in[7];
    const float* b1  = (const float*)d_in[8];
    const float* Ws2 = (const float*)d_in[9];
    const float* Wn2 = (const float*)d_in[10];
    const float* b2  = (const float*)d_in[11];
    float* out = (float*)d_out;

    const int NN = in_sizes[0] / NFEAT;   // 50000
    const int E  = in_sizes[1];           // 800000

    // workspace carve
    char* w = (char*)d_ws;
    float* AGG = (float*)w;  w += align_up((size_t)NN * NFEAT * 4);
    float* H1  = (float*)w;  w += align_up((size_t)NN * NFEAT * 4);
    int* ptrA  = (int*)w;    w += align_up((size_t)(NN + 1) * 4);
    int* deg   = (int*)w;    w += align_up((size_t)NN * 4);
    int* fill  = (int*)w;    w += align_up((size_t)NN * 4);
    int* parts = (int*)w;    w += align_up(256 * 4);
    int* csr   = (int*)w;    w += align_up((size_t)E * 4);

    hipMemsetAsync(deg, 0, (size_t)NN * 4, stream);
    hipMemsetAsync(fill, 0, (size_t)NN * 4, stream);

    const int eb = (E + 255) / 256;
    const int nb = (NN + 255) / 256;   // 196 <= 256, fits single-block scan2

    k_deg<<<eb, 256, 0, stream>>>(dst, deg, E);
    k_scan1<<<nb, 256, 0, stream>>>(deg, ptrA, parts, NN);
    k_scan2<<<1, 256, 0, stream>>>(parts, nb);
    k_scan3<<<nb, 256, 0, stream>>>(ptrA, parts, NN, E);
    k_fill<<<eb, 256, 0, stream>>>(src, dst, ptrA, fill, csr, E);

    const int gm = (NN + 63) / 64;

    // layer 0: x -> H1 (ReLU)
    k_agg<<<NN, 128, 0, stream>>>(x, ptrA, csr, AGG);
    gemm_sage<128><<<gm, 256, 0, stream>>>(x, AGG, Ws0, Wn0, b0, H1, NN, 1);

    // layer 1: H1 -> H1 in-place (ReLU)
    k_agg<<<NN, 128, 0, stream>>>(H1, ptrA, csr, AGG);
    gemm_sage<128><<<gm, 256, 0, stream>>>(H1, AGG, Ws1, Wn1, b1, H1, NN, 1);

    // layer 2: H1 -> out (no ReLU)
    k_agg<<<NN, 128, 0, stream>>>(H1, ptrA, csr, AGG);
    gemm_sage<64><<<gm, 256, 0, stream>>>(H1, AGG, Ws2, Wn2, b2, out, NN, 0);
}

// Round 2
// 358.372 us; speedup vs baseline: 1.4439x; 1.4439x over previous
//
#include <hip/hip_runtime.h>
#include <hip/hip_bf16.h>

// GraphSAGE on MI355X — bf16 internal pipeline.
// CSR build (once/launch) -> per layer: wave-per-node bf16 gather-mean ->
// MFMA bf16 GEMM (K=256 concat [h|h_neigh] x [Ws;Wn]^T) with fp32 accumulate.

#define NFEAT 128

typedef __attribute__((ext_vector_type(8))) short short8;
typedef __attribute__((ext_vector_type(4))) float floatx4;

// ---------------- CSR build ----------------

__global__ void k_deg(const int* __restrict__ dst, int* __restrict__ deg, int E) {
    int e = blockIdx.x * 256 + threadIdx.x;
    if (e < E) atomicAdd(&deg[dst[e]], 1);
}

__global__ void k_scan1(const int* __restrict__ deg, int* __restrict__ ptrA,
                        int* __restrict__ partials, int NN) {
    __shared__ int sh[256];
    int t = threadIdx.x;
    int i = blockIdx.x * 256 + t;
    int v = (i < NN) ? deg[i] : 0;
    sh[t] = v;
    __syncthreads();
#pragma unroll
    for (int off = 1; off < 256; off <<= 1) {
        int x = (t >= off) ? sh[t - off] : 0;
        __syncthreads();
        sh[t] += x;
        __syncthreads();
    }
    if (i < NN) ptrA[i] = sh[t] - v;
    if (t == 255) partials[blockIdx.x] = sh[255];
}

__global__ void k_scan2(int* __restrict__ partials, int nb) {
    __shared__ int sh[256];
    int t = threadIdx.x;
    int v = (t < nb) ? partials[t] : 0;
    sh[t] = v;
    __syncthreads();
#pragma unroll
    for (int off = 1; off < 256; off <<= 1) {
        int x = (t >= off) ? sh[t - off] : 0;
        __syncthreads();
        sh[t] += x;
        __syncthreads();
    }
    if (t < nb) partials[t] = sh[t] - v;
}

__global__ void k_scan3(int* __restrict__ ptrA, const int* __restrict__ partials,
                        int NN, int E) {
    int i = blockIdx.x * 256 + threadIdx.x;
    if (i < NN) ptrA[i] += partials[blockIdx.x];
    if (i == 0) ptrA[NN] = E;
}

__global__ void k_fill(const int* __restrict__ src, const int* __restrict__ dst,
                       const int* __restrict__ ptrA, int* __restrict__ fill,
                       int* __restrict__ csr, int E) {
    int e = blockIdx.x * 256 + threadIdx.x;
    if (e < E) {
        int d = dst[e];
        int pos = ptrA[d] + atomicAdd(&fill[d], 1);
        csr[pos] = src[e];
    }
}

// ---------------- fp32 -> bf16 conversion (x table) ----------------

__global__ void k_cvt_bf16(const float* __restrict__ X, ushort* __restrict__ Y, int n2) {
    int i = blockIdx.x * 256 + threadIdx.x;  // one uint (2 bf16) per thread
    if (i < n2) {
        float2 v = ((const float2*)X)[i];
        __hip_bfloat16 a = __float2bfloat16(v.x), b = __float2bfloat16(v.y);
        unsigned u = (unsigned)(*(unsigned short*)&a) | ((unsigned)(*(unsigned short*)&b) << 16);
        ((unsigned*)Y)[i] = u;
    }
}

// ---------------- weight prep: Wt[n][k] = bf16( k<128 ? Ws[k][n] : Wn[k-128][n] ) ----------------

__global__ void k_wprep(const float* __restrict__ Ws, const float* __restrict__ Wn,
                        ushort* __restrict__ Wt, int No) {
    int idx = blockIdx.x * 256 + threadIdx.x;  // over No*256
    if (idx < No * 256) {
        int n = idx >> 8, k = idx & 255;
        float v = (k < 128) ? Ws[k * No + n] : Wn[(k - 128) * No + n];
        __hip_bfloat16 h = __float2bfloat16(v);
        Wt[idx] = *(unsigned short*)&h;
    }
}

// ---------------- mean aggregation: one wave per node, bf16 table ----------------

__device__ __forceinline__ float bf_lo(unsigned u) { return __uint_as_float(u << 16); }
__device__ __forceinline__ float bf_hi(unsigned u) { return __uint_as_float(u & 0xffff0000u); }

__global__ __launch_bounds__(256) void k_agg16(const ushort* __restrict__ H,
                                               const int* __restrict__ ptrA,
                                               const int* __restrict__ csr,
                                               ushort* __restrict__ AGG, int NN) {
    int node = (blockIdx.x * 256 + threadIdx.x) >> 6;
    int lane = threadIdx.x & 63;               // covers cols 2*lane, 2*lane+1
    if (node >= NN) return;
    const unsigned* Hu = (const unsigned*)H;
    int beg = ptrA[node], end = ptrA[node + 1];
    float a0 = 0.f, a1 = 0.f;
    int e = beg;
    for (; e + 4 <= end; e += 4) {
        int s0 = csr[e], s1 = csr[e + 1], s2 = csr[e + 2], s3 = csr[e + 3];
        unsigned u0 = Hu[(size_t)s0 * 64 + lane];
        unsigned u1 = Hu[(size_t)s1 * 64 + lane];
        unsigned u2 = Hu[(size_t)s2 * 64 + lane];
        unsigned u3 = Hu[(size_t)s3 * 64 + lane];
        a0 += bf_lo(u0) + bf_lo(u1) + bf_lo(u2) + bf_lo(u3);
        a1 += bf_hi(u0) + bf_hi(u1) + bf_hi(u2) + bf_hi(u3);
    }
    for (; e < end; ++e) {
        unsigned u = Hu[(size_t)csr[e] * 64 + lane];
        a0 += bf_lo(u);
        a1 += bf_hi(u);
    }
    int d = end - beg;
    float inv = (d > 0) ? 1.0f / (float)d : 0.0f;
    __hip_bfloat16 r0 = __float2bfloat16(a0 * inv);
    __hip_bfloat16 r1 = __float2bfloat16(a1 * inv);
    unsigned u = (unsigned)(*(unsigned short*)&r0) | ((unsigned)(*(unsigned short*)&r1) << 16);
    ((unsigned*)AGG)[(size_t)node * 64 + lane] = u;
}

// ---------------- MFMA GEMM: C = [H|AGG] @ Wt^T + b (+ReLU) ----------------
// BM=128, BK=32, K=256 (kb 0..3 -> H, 4..7 -> AGG). Waves 2(m) x WN(n),
// wave tile 64x64 -> 4x4 grid of 16x16x32 MFMA. A in LDS [m][k], W pre-
// transposed [n][k]; rows padded to 40 ushorts (80B) -> conflict-free b128.

template <int BN, bool OUT_BF16>
__global__ __launch_bounds__(64 * 2 * (BN / 64)) void gemm_mfma(
    const ushort* __restrict__ Hs, const ushort* __restrict__ Ag,
    const ushort* __restrict__ Wt, const float* __restrict__ bias,
    void* __restrict__ Cout, int M, int relu) {
    constexpr int WN = BN / 64;
    constexpr int NTHR = 64 * 2 * WN;
    constexpr int LDA = 40;                    // padded row stride (ushorts)
    __shared__ ushort Asl[128 * LDA];
    __shared__ ushort Bsl[BN * LDA];

    int t = threadIdx.x;
    int lane = t & 63;
    int wid = t >> 6;
    int wm = wid & 1, wn = wid >> 1;
    int l15 = lane & 15, quad = lane >> 4;
    int m0 = blockIdx.x * 128;

    floatx4 acc[4][4] = {};

    for (int kb = 0; kb < 8; ++kb) {
        const ushort* Asrc = (kb < 4) ? Hs : Ag;
        int kOff = (kb & 3) * 32;
        __syncthreads();
        // stage A tile: 128 rows x 32 k, uint4 chunks of 8 bf16
#pragma unroll
        for (int id = t; id < 128 * 4; id += NTHR) {
            int r = id >> 2, p = id & 3;
            uint4 v = make_uint4(0, 0, 0, 0);
            if (m0 + r < M) v = *(const uint4*)(Asrc + (size_t)(m0 + r) * NFEAT + kOff + p * 8);
            *(uint4*)(&Asl[r * LDA + p * 8]) = v;
        }
        // stage B tile: BN rows x 32 k from Wt[n][256]
#pragma unroll
        for (int id = t; id < BN * 4; id += NTHR) {
            int r = id >> 2, p = id & 3;
            uint4 v = *(const uint4*)(Wt + (size_t)r * 256 + kb * 32 + p * 8);
            *(uint4*)(&Bsl[r * LDA + p * 8]) = v;
        }
        __syncthreads();

        short8 a[4], b[4];
#pragma unroll
        for (int mt = 0; mt < 4; ++mt)
            a[mt] = *(const short8*)(&Asl[(wm * 64 + mt * 16 + l15) * LDA + quad * 8]);
#pragma unroll
        for (int nt = 0; nt < 4; ++nt)
            b[nt] = *(const short8*)(&Bsl[(wn * 64 + nt * 16 + l15) * LDA + quad * 8]);
#pragma unroll
        for (int mt = 0; mt < 4; ++mt)
#pragma unroll
            for (int nt = 0; nt < 4; ++nt)
                acc[mt][nt] = __builtin_amdgcn_mfma_f32_16x16x32_bf16(a[mt], b[nt], acc[mt][nt], 0, 0, 0);
    }

    // epilogue: C/D layout col=lane&15, row=quad*4+reg
#pragma unroll
    for (int mt = 0; mt < 4; ++mt) {
        int mbase = m0 + wm * 64 + mt * 16 + quad * 4;
#pragma unroll
        for (int nt = 0; nt < 4; ++nt) {
            int col = wn * 64 + nt * 16 + l15;
            float bv = bias[col];
#pragma unroll
            for (int r = 0; r < 4; ++r) {
                int m = mbase + r;
                if (m < M) {
                    float v = acc[mt][nt][r] + bv;
                    if (relu) v = fmaxf(v, 0.f);
                    if constexpr (OUT_BF16) {
                        __hip_bfloat16 h = __float2bfloat16(v);
                        ((unsigned short*)Cout)[(size_t)m * BN + col] = *(unsigned short*)&h;
                    } else {
                        ((float*)Cout)[(size_t)m * BN + col] = v;
                    }
                }
            }
        }
    }
}

// ---------------- launch ----------------

static inline size_t align_up(size_t x) { return (x + 255) & ~(size_t)255; }

extern "C" void kernel_launch(void* const* d_in, const int* in_sizes, int n_in,
                              void* d_out, int out_size, void* d_ws, size_t ws_size,
                              hipStream_t stream) {
    const float* x   = (const float*)d_in[0];
    const int*   src = (const int*)d_in[1];
    const int*   dst = (const int*)d_in[2];
    const float* Ws0 = (const float*)d_in[3];
    const float* Wn0 = (const float*)d_in[4];
    const float* b0  = (const float*)d_in[5];
    const float* Ws1 = (const float*)d_in[6];
    const float* Wn1 = (const float*)d_in[7];
    const float* b1  = (const float*)d_in[8];
    const float* Ws2 = (const float*)d_in[9];
    const float* Wn2 = (const float*)d_in[10];
    const float* b2  = (const float*)d_in[11];
    float* out = (float*)d_out;

    const int NN = in_sizes[0] / NFEAT;   // 50000
    const int E  = in_sizes[1];           // 800000

    char* w = (char*)d_ws;
    ushort* X16  = (ushort*)w; w += align_up((size_t)NN * NFEAT * 2);
    ushort* Ha   = (ushort*)w; w += align_up((size_t)NN * NFEAT * 2);
    ushort* Hb   = (ushort*)w; w += align_up((size_t)NN * NFEAT * 2);
    ushort* AGG  = (ushort*)w; w += align_up((size_t)NN * NFEAT * 2);
    ushort* Wt0  = (ushort*)w; w += align_up((size_t)128 * 256 * 2);
    ushort* Wt1  = (ushort*)w; w += align_up((size_t)128 * 256 * 2);
    ushort* Wt2  = (ushort*)w; w += align_up((size_t)64 * 256 * 2);
    int* ptrA    = (int*)w;    w += align_up((size_t)(NN + 1) * 4);
    int* deg     = (int*)w;    w += align_up((size_t)NN * 4);
    int* fill    = (int*)w;    w += align_up((size_t)NN * 4);
    int* parts   = (int*)w;    w += align_up(256 * 4);
    int* csr     = (int*)w;    w += align_up((size_t)E * 4);

    hipMemsetAsync(deg, 0, (size_t)NN * 4, stream);
    hipMemsetAsync(fill, 0, (size_t)NN * 4, stream);

    const int eb = (E + 255) / 256;
    const int nb = (NN + 255) / 256;      // 196 <= 256: single-block scan2 ok

    k_deg<<<eb, 256, 0, stream>>>(dst, deg, E);
    k_scan1<<<nb, 256, 0, stream>>>(deg, ptrA, parts, NN);
    k_scan2<<<1, 256, 0, stream>>>(parts, nb);
    k_scan3<<<nb, 256, 0, stream>>>(ptrA, parts, NN, E);
    k_fill<<<eb, 256, 0, stream>>>(src, dst, ptrA, fill, csr, E);

    // conversions
    const int n2 = NN * NFEAT / 2;
    k_cvt_bf16<<<(n2 + 255) / 256, 256, 0, stream>>>(x, X16, n2);
    k_wprep<<<(128 * 256 + 255) / 256, 256, 0, stream>>>(Ws0, Wn0, Wt0, 128);
    k_wprep<<<(128 * 256 + 255) / 256, 256, 0, stream>>>(Ws1, Wn1, Wt1, 128);
    k_wprep<<<(64 * 256 + 255) / 256, 256, 0, stream>>>(Ws2, Wn2, Wt2, 64);

    const int ab = (NN * 64 + 255) / 256;       // wave-per-node agg blocks
    const int gm = (NN + 127) / 128;            // 391 GEMM blocks

    // layer 0: X16 -> Ha (ReLU)
    k_agg16<<<ab, 256, 0, stream>>>(X16, ptrA, csr, AGG, NN);
    gemm_mfma<128, true><<<gm, 256, 0, stream>>>(X16, AGG, Wt0, b0, Ha, NN, 1);

    // layer 1: Ha -> Hb (ReLU)
    k_agg16<<<ab, 256, 0, stream>>>(Ha, ptrA, csr, AGG, NN);
    gemm_mfma<128, true><<<gm, 256, 0, stream>>>(Ha, AGG, Wt1, b1, Hb, NN, 1);

    // layer 2: Hb -> out fp32 (no ReLU)
    k_agg16<<<ab, 256, 0, stream>>>(Hb, ptrA, csr, AGG, NN);
    gemm_mfma<64, false><<<gm, 128, 0, stream>>>(Hb, AGG, Wt2, b2, out, NN, 0);
}

// Round 3
// 339.971 us; speedup vs baseline: 1.5220x; 1.0541x over previous
//
#include <hip/hip_runtime.h>
#include <hip/hip_bf16.h>

// GraphSAGE on MI355X — bf16 internal pipeline, round 3.
// CSR build: rank captured by the counting atomic (fill pass is atomic-free
// pure scatter). Aggregation: 16 lanes x 16B per row -> 4 edges per wave-iter.
// Layer 2 uses agg(h@Wn) == agg(h)@Wn to halve gather traffic (64-wide table).

#define NFEAT 128

typedef __attribute__((ext_vector_type(8))) short short8;
typedef __attribute__((ext_vector_type(4))) float floatx4;

// ---------------- CSR build ----------------

__global__ __launch_bounds__(256) void k_rank(const int* __restrict__ dst,
                                              int* __restrict__ deg,
                                              int* __restrict__ rnk, int E) {
    int base = (blockIdx.x * 256 + threadIdx.x) * 4;
    if (base + 4 <= E) {
        int4 d4 = *(const int4*)(dst + base);
        int4 r4;
        r4.x = atomicAdd(&deg[d4.x], 1);
        r4.y = atomicAdd(&deg[d4.y], 1);
        r4.z = atomicAdd(&deg[d4.z], 1);
        r4.w = atomicAdd(&deg[d4.w], 1);
        *(int4*)(rnk + base) = r4;
    } else {
        for (int e = base; e < E; ++e) rnk[e] = atomicAdd(&deg[dst[e]], 1);
    }
}

__global__ void k_scan1(const int* __restrict__ deg, int* __restrict__ ptrA,
                        int* __restrict__ partials, int NN) {
    __shared__ int sh[256];
    int t = threadIdx.x;
    int i = blockIdx.x * 256 + t;
    int v = (i < NN) ? deg[i] : 0;
    sh[t] = v;
    __syncthreads();
#pragma unroll
    for (int off = 1; off < 256; off <<= 1) {
        int x = (t >= off) ? sh[t - off] : 0;
        __syncthreads();
        sh[t] += x;
        __syncthreads();
    }
    if (i < NN) ptrA[i] = sh[t] - v;
    if (t == 255) partials[blockIdx.x] = sh[255];
}

__global__ void k_scan2(int* __restrict__ partials, int nb) {
    __shared__ int sh[256];
    int t = threadIdx.x;
    int v = (t < nb) ? partials[t] : 0;
    sh[t] = v;
    __syncthreads();
#pragma unroll
    for (int off = 1; off < 256; off <<= 1) {
        int x = (t >= off) ? sh[t - off] : 0;
        __syncthreads();
        sh[t] += x;
        __syncthreads();
    }
    if (t < nb) partials[t] = sh[t] - v;
}

__global__ void k_scan3(int* __restrict__ ptrA, const int* __restrict__ partials,
                        int NN, int E) {
    int i = blockIdx.x * 256 + threadIdx.x;
    if (i < NN) ptrA[i] += partials[blockIdx.x];
    if (i == 0) ptrA[NN] = E;
}

__global__ __launch_bounds__(256) void k_fill2(const int* __restrict__ src,
                                               const int* __restrict__ dst,
                                               const int* __restrict__ rnk,
                                               const int* __restrict__ ptrA,
                                               int* __restrict__ csr, int E) {
    int base = (blockIdx.x * 256 + threadIdx.x) * 4;
    if (base + 4 <= E) {
        int4 d4 = *(const int4*)(dst + base);
        int4 r4 = *(const int4*)(rnk + base);
        int4 s4 = *(const int4*)(src + base);
        csr[ptrA[d4.x] + r4.x] = s4.x;
        csr[ptrA[d4.y] + r4.y] = s4.y;
        csr[ptrA[d4.z] + r4.z] = s4.z;
        csr[ptrA[d4.w] + r4.w] = s4.w;
    } else {
        for (int e = base; e < E; ++e) csr[ptrA[dst[e]] + rnk[e]] = src[e];
    }
}

// ---------------- fp32 -> bf16 conversion (x table) ----------------

__global__ void k_cvt_bf16(const float* __restrict__ X, ushort* __restrict__ Y, int n2) {
    int i = blockIdx.x * 256 + threadIdx.x;
    if (i < n2) {
        float2 v = ((const float2*)X)[i];
        __hip_bfloat16 a = __float2bfloat16(v.x), b = __float2bfloat16(v.y);
        unsigned u = (unsigned)(*(unsigned short*)&a) | ((unsigned)(*(unsigned short*)&b) << 16);
        ((unsigned*)Y)[i] = u;
    }
}

// ---------------- weight prep: Wt[n][k] = bf16( k<128 ? Ws[k][n] : Wn[k-128][n] ) ----------------

__global__ void k_wprep(const float* __restrict__ Ws, const float* __restrict__ Wn,
                        ushort* __restrict__ Wt, int No) {
    int idx = blockIdx.x * 256 + threadIdx.x;
    if (idx < No * 256) {
        int n = idx >> 8, k = idx & 255;
        float v = (k < 128) ? Ws[k * No + n] : Wn[(k - 128) * No + n];
        __hip_bfloat16 h = __float2bfloat16(v);
        Wt[idx] = *(unsigned short*)&h;
    }
}

// ---------------- mean aggregation: one wave per node, multi-edge per iter ----------------

__device__ __forceinline__ float bf_lo(unsigned u) { return __uint_as_float(u << 16); }
__device__ __forceinline__ float bf_hi(unsigned u) { return __uint_as_float(u & 0xffff0000u); }

template <int FEAT, bool OUT_BF16>
__global__ __launch_bounds__(256) void k_agg_t(const ushort* __restrict__ H,
                                               const int* __restrict__ ptrA,
                                               const int* __restrict__ csr,
                                               void* __restrict__ outp, int NN) {
    constexpr int LPR = FEAT / 8;   // lanes per row (16B chunks of 8 bf16)
    constexpr int EPG = 64 / LPR;   // edges processed per wave-iteration
    int node = (blockIdx.x * 256 + threadIdx.x) >> 6;
    if (node >= NN) return;
    int lane = threadIdx.x & 63;
    int sub = lane / LPR, fl = lane % LPR;
    int beg = ptrA[node], end = ptrA[node + 1];
    float acc[8] = {};
    for (int e = beg + sub; e < end; e += EPG) {
        int r = csr[e];
        uint4 v = *(const uint4*)(H + (size_t)r * FEAT + fl * 8);
        acc[0] += bf_lo(v.x); acc[1] += bf_hi(v.x);
        acc[2] += bf_lo(v.y); acc[3] += bf_hi(v.y);
        acc[4] += bf_lo(v.z); acc[5] += bf_hi(v.z);
        acc[6] += bf_lo(v.w); acc[7] += bf_hi(v.w);
    }
#pragma unroll
    for (int off = LPR; off < 64; off <<= 1)
#pragma unroll
        for (int i = 0; i < 8; ++i) acc[i] += __shfl_xor(acc[i], off, 64);
    if (sub == 0) {
        int d = end - beg;
        float inv = (d > 0) ? 1.0f / (float)d : 0.0f;
        if constexpr (OUT_BF16) {
            unsigned u[4];
#pragma unroll
            for (int i = 0; i < 4; ++i) {
                __hip_bfloat16 l = __float2bfloat16(acc[2 * i] * inv);
                __hip_bfloat16 h = __float2bfloat16(acc[2 * i + 1] * inv);
                u[i] = (unsigned)(*(unsigned short*)&l) | ((unsigned)(*(unsigned short*)&h) << 16);
            }
            *(uint4*)((ushort*)outp + (size_t)node * FEAT + fl * 8) =
                make_uint4(u[0], u[1], u[2], u[3]);
        } else {
            float* O = (float*)outp;
            size_t b = (size_t)node * FEAT + fl * 8;
#pragma unroll
            for (int i = 0; i < 8; ++i) O[b + i] = acc[i] * inv;
        }
    }
}

// ---------------- MFMA GEMM ----------------
// C = A @ Wt^T (+bias) (+addin) (+ReLU). SPLIT: A = [Hs | Ag] along K.
// BM=128, BK=32. Waves 2(m) x BN/64(n), wave tile 64x64 of 16x16x32 MFMA.
// LDS rows padded to 40 ushorts (80B) -> conflict-free ds_read_b128.

template <int BN, int NKB, bool SPLIT, bool OUT_BF16>
__global__ __launch_bounds__(64 * 2 * (BN / 64)) void gemm_mfma(
    const ushort* __restrict__ Hs, const ushort* __restrict__ Ag,
    const ushort* __restrict__ Wt, int ldw, const float* __restrict__ bias,
    const float* __restrict__ addin, void* __restrict__ Cout, int M, int relu) {
    constexpr int WN = BN / 64;
    constexpr int NTHR = 64 * 2 * WN;
    constexpr int LDA = 40;
    __shared__ ushort Asl[128 * LDA];
    __shared__ ushort Bsl[BN * LDA];

    int t = threadIdx.x;
    int lane = t & 63;
    int wid = t >> 6;
    int wm = wid & 1, wn = wid >> 1;
    int l15 = lane & 15, quad = lane >> 4;
    int m0 = blockIdx.x * 128;

    floatx4 acc[4][4] = {};

    for (int kb = 0; kb < NKB; ++kb) {
        const ushort* Asrc;
        int kOff;
        if constexpr (SPLIT) {
            Asrc = (kb < NKB / 2) ? Hs : Ag;
            kOff = (kb & (NKB / 2 - 1)) * 32;
        } else {
            Asrc = Hs;
            kOff = kb * 32;
        }
        __syncthreads();
#pragma unroll
        for (int id = t; id < 128 * 4; id += NTHR) {
            int r = id >> 2, p = id & 3;
            uint4 v = make_uint4(0, 0, 0, 0);
            if (m0 + r < M) v = *(const uint4*)(Asrc + (size_t)(m0 + r) * NFEAT + kOff + p * 8);
            *(uint4*)(&Asl[r * LDA + p * 8]) = v;
        }
#pragma unroll
        for (int id = t; id < BN * 4; id += NTHR) {
            int r = id >> 2, p = id & 3;
            uint4 v = *(const uint4*)(Wt + (size_t)r * ldw + kb * 32 + p * 8);
            *(uint4*)(&Bsl[r * LDA + p * 8]) = v;
        }
        __syncthreads();

        short8 a[4], b[4];
#pragma unroll
        for (int mt = 0; mt < 4; ++mt)
            a[mt] = *(const short8*)(&Asl[(wm * 64 + mt * 16 + l15) * LDA + quad * 8]);
#pragma unroll
        for (int nt = 0; nt < 4; ++nt)
            b[nt] = *(const short8*)(&Bsl[(wn * 64 + nt * 16 + l15) * LDA + quad * 8]);
#pragma unroll
        for (int mt = 0; mt < 4; ++mt)
#pragma unroll
            for (int nt = 0; nt < 4; ++nt)
                acc[mt][nt] = __builtin_amdgcn_mfma_f32_16x16x32_bf16(a[mt], b[nt], acc[mt][nt], 0, 0, 0);
    }

#pragma unroll
    for (int mt = 0; mt < 4; ++mt) {
        int mbase = m0 + wm * 64 + mt * 16 + quad * 4;
#pragma unroll
        for (int nt = 0; nt < 4; ++nt) {
            int col = wn * 64 + nt * 16 + l15;
            float bv = bias ? bias[col] : 0.0f;
#pragma unroll
            for (int r = 0; r < 4; ++r) {
                int m = mbase + r;
                if (m < M) {
                    float v = acc[mt][nt][r] + bv;
                    if (addin) v += addin[(size_t)m * BN + col];
                    if (relu) v = fmaxf(v, 0.f);
                    if constexpr (OUT_BF16) {
                        __hip_bfloat16 h = __float2bfloat16(v);
                        ((unsigned short*)Cout)[(size_t)m * BN + col] = *(unsigned short*)&h;
                    } else {
                        ((float*)Cout)[(size_t)m * BN + col] = v;
                    }
                }
            }
        }
    }
}

// ---------------- launch ----------------

static inline size_t align_up(size_t x) { return (x + 255) & ~(size_t)255; }

extern "C" void kernel_launch(void* const* d_in, const int* in_sizes, int n_in,
                              void* d_out, int out_size, void* d_ws, size_t ws_size,
                              hipStream_t stream) {
    const float* x   = (const float*)d_in[0];
    const int*   src = (const int*)d_in[1];
    const int*   dst = (const int*)d_in[2];
    const float* Ws0 = (const float*)d_in[3];
    const float* Wn0 = (const float*)d_in[4];
    const float* b0  = (const float*)d_in[5];
    const float* Ws1 = (const float*)d_in[6];
    const float* Wn1 = (const float*)d_in[7];
    const float* b1  = (const float*)d_in[8];
    const float* Ws2 = (const float*)d_in[9];
    const float* Wn2 = (const float*)d_in[10];
    const float* b2  = (const float*)d_in[11];
    float* out = (float*)d_out;

    const int NN = in_sizes[0] / NFEAT;   // 50000
    const int E  = in_sizes[1];           // 800000

    char* w = (char*)d_ws;
    ushort* X16  = (ushort*)w; w += align_up((size_t)NN * NFEAT * 2);
    ushort* Ha   = (ushort*)w; w += align_up((size_t)NN * NFEAT * 2);
    ushort* Hb   = (ushort*)w; w += align_up((size_t)NN * NFEAT * 2);
    ushort* AGG  = (ushort*)w; w += align_up((size_t)NN * NFEAT * 2);
    ushort* Wt0  = (ushort*)w; w += align_up((size_t)128 * 256 * 2);
    ushort* Wt1  = (ushort*)w; w += align_up((size_t)128 * 256 * 2);
    ushort* Wt2  = (ushort*)w; w += align_up((size_t)64 * 256 * 2);
    int* ptrA    = (int*)w;    w += align_up((size_t)(NN + 1) * 4);
    int* deg     = (int*)w;    w += align_up((size_t)NN * 4);
    int* parts   = (int*)w;    w += align_up(256 * 4);
    int* csr     = (int*)w;    w += align_up((size_t)E * 4);

    // aliased scratch (lifetimes disjoint):
    int*    rnk = (int*)Ha;      // used only during CSR build, before Ha written
    ushort* G2  = X16;           // layer-2 neighbor-projected table, after X16 dead
    float*  A2  = (float*)AGG;   // layer-2 fp32 aggregate, after AGG dead

    hipMemsetAsync(deg, 0, (size_t)NN * 4, stream);

    const int e4b = (E / 4 + 255) / 256;
    const int nb  = (NN + 255) / 256;    // 196 <= 256: single-block scan2 ok

    k_rank<<<e4b, 256, 0, stream>>>(dst, deg, rnk, E);
    k_scan1<<<nb, 256, 0, stream>>>(deg, ptrA, parts, NN);
    k_scan2<<<1, 256, 0, stream>>>(parts, nb);
    k_scan3<<<nb, 256, 0, stream>>>(ptrA, parts, NN, E);
    k_fill2<<<e4b, 256, 0, stream>>>(src, dst, rnk, ptrA, csr, E);

    const int n2 = NN * NFEAT / 2;
    k_cvt_bf16<<<(n2 + 255) / 256, 256, 0, stream>>>(x, X16, n2);
    k_wprep<<<(128 * 256 + 255) / 256, 256, 0, stream>>>(Ws0, Wn0, Wt0, 128);
    k_wprep<<<(128 * 256 + 255) / 256, 256, 0, stream>>>(Ws1, Wn1, Wt1, 128);
    k_wprep<<<(64 * 256 + 255) / 256, 256, 0, stream>>>(Ws2, Wn2, Wt2, 64);

    const int ab = (NN * 64 + 255) / 256;
    const int gm = (NN + 127) / 128;

    // layer 0: X16 -> Ha (ReLU)
    k_agg_t<128, true><<<ab, 256, 0, stream>>>(X16, ptrA, csr, AGG, NN);
    gemm_mfma<128, 8, true, true><<<gm, 256, 0, stream>>>(X16, AGG, Wt0, 256, b0, nullptr, Ha, NN, 1);

    // layer 1: Ha -> Hb (ReLU)
    k_agg_t<128, true><<<ab, 256, 0, stream>>>(Ha, ptrA, csr, AGG, NN);
    gemm_mfma<128, 8, true, true><<<gm, 256, 0, stream>>>(Ha, AGG, Wt1, 256, b1, nullptr, Hb, NN, 1);

    // layer 2: agg(Hb)@Wn2 == agg(Hb@Wn2) -> 64-wide gather table
    gemm_mfma<64, 4, false, true><<<gm, 128, 0, stream>>>(Hb, nullptr, Wt2 + 128, 256, nullptr, nullptr, G2, NN, 0);
    k_agg_t<64, false><<<ab, 256, 0, stream>>>(G2, ptrA, csr, A2, NN);
    gemm_mfma<64, 4, false, false><<<gm, 128, 0, stream>>>(Hb, nullptr, Wt2, 256, b2, A2, out, NN, 0);
}

// Round 4
// 328.190 us; speedup vs baseline: 1.5767x; 1.0359x over previous
//
#include <hip/hip_runtime.h>
#include <hip/hip_bf16.h>

// GraphSAGE on MI355X — bf16 internal pipeline, round 4.
// CSR build with 4-way split counters (quarter = e&3) to cut per-line atomic
// contention 4x; quarter offsets folded into the scan. Aggregation gather
// loop 2x unrolled for MLP. Layer 2 uses agg(h@Wn) == agg(h)@Wn.

#define NFEAT 128

typedef __attribute__((ext_vector_type(8))) short short8;
typedef __attribute__((ext_vector_type(4))) float floatx4;

// ---------------- CSR build ----------------

__global__ __launch_bounds__(256) void k_count(const int* __restrict__ dst,
                                               int* __restrict__ deg4,
                                               int* __restrict__ rnk, int E, int NN) {
    int base = (blockIdx.x * 256 + threadIdx.x) * 4;
    if (base + 4 <= E) {
        int4 d4 = *(const int4*)(dst + base);
        int4 r4;
        r4.x = atomicAdd(&deg4[0 * NN + d4.x], 1);
        r4.y = atomicAdd(&deg4[1 * NN + d4.y], 1);
        r4.z = atomicAdd(&deg4[2 * NN + d4.z], 1);
        r4.w = atomicAdd(&deg4[3 * NN + d4.w], 1);
        *(int4*)(rnk + base) = r4;
    } else {
        for (int e = base; e < E; ++e)
            rnk[e] = atomicAdd(&deg4[(e & 3) * NN + dst[e]], 1);
    }
}

// block-local exclusive scan of total degree; also emits quarter offsets
__global__ void k_scan1(const int* __restrict__ deg4, int* __restrict__ off1,
                        int* __restrict__ off2, int* __restrict__ off3,
                        int* __restrict__ ptrA, int* __restrict__ partials, int NN) {
    __shared__ int sh[256];
    int t = threadIdx.x;
    int i = blockIdx.x * 256 + t;
    int d0 = 0, d1 = 0, d2 = 0, d3 = 0;
    if (i < NN) {
        d0 = deg4[i]; d1 = deg4[NN + i]; d2 = deg4[2 * NN + i]; d3 = deg4[3 * NN + i];
        off1[i] = d0; off2[i] = d0 + d1; off3[i] = d0 + d1 + d2;
    }
    int v = d0 + d1 + d2 + d3;
    sh[t] = v;
    __syncthreads();
#pragma unroll
    for (int off = 1; off < 256; off <<= 1) {
        int x = (t >= off) ? sh[t - off] : 0;
        __syncthreads();
        sh[t] += x;
        __syncthreads();
    }
    if (i < NN) ptrA[i] = sh[t] - v;
    if (t == 255) partials[blockIdx.x] = sh[255];
}

__global__ void k_scan2(int* __restrict__ partials, int nb) {
    __shared__ int sh[256];
    int t = threadIdx.x;
    int v = (t < nb) ? partials[t] : 0;
    sh[t] = v;
    __syncthreads();
#pragma unroll
    for (int off = 1; off < 256; off <<= 1) {
        int x = (t >= off) ? sh[t - off] : 0;
        __syncthreads();
        sh[t] += x;
        __syncthreads();
    }
    if (t < nb) partials[t] = sh[t] - v;
}

__global__ void k_scan3(int* __restrict__ ptrA, const int* __restrict__ partials,
                        int NN, int E) {
    int i = blockIdx.x * 256 + threadIdx.x;
    if (i < NN) ptrA[i] += partials[blockIdx.x];
    if (i == 0) ptrA[NN] = E;
}

__global__ __launch_bounds__(256) void k_scatter(const int* __restrict__ src,
                                                 const int* __restrict__ dst,
                                                 const int* __restrict__ rnk,
                                                 const int* __restrict__ ptrA,
                                                 const int* __restrict__ off1,
                                                 const int* __restrict__ off2,
                                                 const int* __restrict__ off3,
                                                 int* __restrict__ csr, int E) {
    int base = (blockIdx.x * 256 + threadIdx.x) * 4;
    if (base + 4 <= E) {
        int4 d4 = *(const int4*)(dst + base);
        int4 r4 = *(const int4*)(rnk + base);
        int4 s4 = *(const int4*)(src + base);
        csr[ptrA[d4.x] + r4.x] = s4.x;
        csr[ptrA[d4.y] + off1[d4.y] + r4.y] = s4.y;
        csr[ptrA[d4.z] + off2[d4.z] + r4.z] = s4.z;
        csr[ptrA[d4.w] + off3[d4.w] + r4.w] = s4.w;
    } else {
        for (int e = base; e < E; ++e) {
            int d = dst[e], q = e & 3;
            int off = (q == 0) ? 0 : ((q == 1) ? off1[d] : ((q == 2) ? off2[d] : off3[d]));
            csr[ptrA[d] + off + rnk[e]] = src[e];
        }
    }
}

// ---------------- fp32 -> bf16 conversion (x table) ----------------

__global__ void k_cvt_bf16(const float* __restrict__ X, ushort* __restrict__ Y, int n2) {
    int i = blockIdx.x * 256 + threadIdx.x;
    if (i < n2) {
        float2 v = ((const float2*)X)[i];
        __hip_bfloat16 a = __float2bfloat16(v.x), b = __float2bfloat16(v.y);
        unsigned u = (unsigned)(*(unsigned short*)&a) | ((unsigned)(*(unsigned short*)&b) << 16);
        ((unsigned*)Y)[i] = u;
    }
}

// ---------------- weight prep: Wt[n][k] = bf16( k<128 ? Ws[k][n] : Wn[k-128][n] ) ----------------

__global__ void k_wprep(const float* __restrict__ Ws, const float* __restrict__ Wn,
                        ushort* __restrict__ Wt, int No) {
    int idx = blockIdx.x * 256 + threadIdx.x;
    if (idx < No * 256) {
        int n = idx >> 8, k = idx & 255;
        float v = (k < 128) ? Ws[k * No + n] : Wn[(k - 128) * No + n];
        __hip_bfloat16 h = __float2bfloat16(v);
        Wt[idx] = *(unsigned short*)&h;
    }
}

// ---------------- mean aggregation: one wave per node, multi-edge per iter ----------------

__device__ __forceinline__ float bf_lo(unsigned u) { return __uint_as_float(u << 16); }
__device__ __forceinline__ float bf_hi(unsigned u) { return __uint_as_float(u & 0xffff0000u); }

template <int FEAT, bool OUT_BF16>
__global__ __launch_bounds__(256) void k_agg_t(const ushort* __restrict__ H,
                                               const int* __restrict__ ptrA,
                                               const int* __restrict__ csr,
                                               void* __restrict__ outp, int NN) {
    constexpr int LPR = FEAT / 8;   // lanes per row (16B chunks of 8 bf16)
    constexpr int EPG = 64 / LPR;   // edges per wave-iteration
    int node = (blockIdx.x * 256 + threadIdx.x) >> 6;
    if (node >= NN) return;
    int lane = threadIdx.x & 63;
    int sub = lane / LPR, fl = lane % LPR;
    int beg = ptrA[node], end = ptrA[node + 1];
    float acc[8] = {};
    int e = beg + sub;
    // 2x unrolled: two independent row-gathers in flight per lane
    for (; e + EPG < end; e += 2 * EPG) {
        int r0 = csr[e], r1 = csr[e + EPG];
        uint4 v0 = *(const uint4*)(H + (size_t)r0 * FEAT + fl * 8);
        uint4 v1 = *(const uint4*)(H + (size_t)r1 * FEAT + fl * 8);
        acc[0] += bf_lo(v0.x); acc[1] += bf_hi(v0.x);
        acc[2] += bf_lo(v0.y); acc[3] += bf_hi(v0.y);
        acc[4] += bf_lo(v0.z); acc[5] += bf_hi(v0.z);
        acc[6] += bf_lo(v0.w); acc[7] += bf_hi(v0.w);
        acc[0] += bf_lo(v1.x); acc[1] += bf_hi(v1.x);
        acc[2] += bf_lo(v1.y); acc[3] += bf_hi(v1.y);
        acc[4] += bf_lo(v1.z); acc[5] += bf_hi(v1.z);
        acc[6] += bf_lo(v1.w); acc[7] += bf_hi(v1.w);
    }
    for (; e < end; e += EPG) {
        int r = csr[e];
        uint4 v = *(const uint4*)(H + (size_t)r * FEAT + fl * 8);
        acc[0] += bf_lo(v.x); acc[1] += bf_hi(v.x);
        acc[2] += bf_lo(v.y); acc[3] += bf_hi(v.y);
        acc[4] += bf_lo(v.z); acc[5] += bf_hi(v.z);
        acc[6] += bf_lo(v.w); acc[7] += bf_hi(v.w);
    }
#pragma unroll
    for (int off = LPR; off < 64; off <<= 1)
#pragma unroll
        for (int i = 0; i < 8; ++i) acc[i] += __shfl_xor(acc[i], off, 64);
    if (sub == 0) {
        int d = end - beg;
        float inv = (d > 0) ? 1.0f / (float)d : 0.0f;
        if constexpr (OUT_BF16) {
            unsigned u[4];
#pragma unroll
            for (int i = 0; i < 4; ++i) {
                __hip_bfloat16 l = __float2bfloat16(acc[2 * i] * inv);
                __hip_bfloat16 h = __float2bfloat16(acc[2 * i + 1] * inv);
                u[i] = (unsigned)(*(unsigned short*)&l) | ((unsigned)(*(unsigned short*)&h) << 16);
            }
            *(uint4*)((ushort*)outp + (size_t)node * FEAT + fl * 8) =
                make_uint4(u[0], u[1], u[2], u[3]);
        } else {
            float* O = (float*)outp;
            size_t b = (size_t)node * FEAT + fl * 8;
#pragma unroll
            for (int i = 0; i < 8; ++i) O[b + i] = acc[i] * inv;
        }
    }
}

// ---------------- MFMA GEMM ----------------
// C = A @ Wt^T (+bias) (+addin) (+ReLU). SPLIT: A = [Hs | Ag] along K.
// BM=128, BK=32. Waves 2(m) x BN/64(n), wave tile 64x64 of 16x16x32 MFMA.
// LDS rows padded to 40 ushorts (80B) -> conflict-free ds_read_b128.

template <int BN, int NKB, bool SPLIT, bool OUT_BF16>
__global__ __launch_bounds__(64 * 2 * (BN / 64)) void gemm_mfma(
    const ushort* __restrict__ Hs, const ushort* __restrict__ Ag,
    const ushort* __restrict__ Wt, int ldw, const float* __restrict__ bias,
    const float* __restrict__ addin, void* __restrict__ Cout, int M, int relu) {
    constexpr int WN = BN / 64;
    constexpr int NTHR = 64 * 2 * WN;
    constexpr int LDA = 40;
    __shared__ ushort Asl[128 * LDA];
    __shared__ ushort Bsl[BN * LDA];

    int t = threadIdx.x;
    int lane = t & 63;
    int wid = t >> 6;
    int wm = wid & 1, wn = wid >> 1;
    int l15 = lane & 15, quad = lane >> 4;
    int m0 = blockIdx.x * 128;

    floatx4 acc[4][4] = {};

    for (int kb = 0; kb < NKB; ++kb) {
        const ushort* Asrc;
        int kOff;
        if constexpr (SPLIT) {
            Asrc = (kb < NKB / 2) ? Hs : Ag;
            kOff = (kb & (NKB / 2 - 1)) * 32;
        } else {
            Asrc = Hs;
            kOff = kb * 32;
        }
        __syncthreads();
#pragma unroll
        for (int id = t; id < 128 * 4; id += NTHR) {
            int r = id >> 2, p = id & 3;
            uint4 v = make_uint4(0, 0, 0, 0);
            if (m0 + r < M) v = *(const uint4*)(Asrc + (size_t)(m0 + r) * NFEAT + kOff + p * 8);
            *(uint4*)(&Asl[r * LDA + p * 8]) = v;
        }
#pragma unroll
        for (int id = t; id < BN * 4; id += NTHR) {
            int r = id >> 2, p = id & 3;
            uint4 v = *(const uint4*)(Wt + (size_t)r * ldw + kb * 32 + p * 8);
            *(uint4*)(&Bsl[r * LDA + p * 8]) = v;
        }
        __syncthreads();

        short8 a[4], b[4];
#pragma unroll
        for (int mt = 0; mt < 4; ++mt)
            a[mt] = *(const short8*)(&Asl[(wm * 64 + mt * 16 + l15) * LDA + quad * 8]);
#pragma unroll
        for (int nt = 0; nt < 4; ++nt)
            b[nt] = *(const short8*)(&Bsl[(wn * 64 + nt * 16 + l15) * LDA + quad * 8]);
#pragma unroll
        for (int mt = 0; mt < 4; ++mt)
#pragma unroll
            for (int nt = 0; nt < 4; ++nt)
                acc[mt][nt] = __builtin_amdgcn_mfma_f32_16x16x32_bf16(a[mt], b[nt], acc[mt][nt], 0, 0, 0);
    }

#pragma unroll
    for (int mt = 0; mt < 4; ++mt) {
        int mbase = m0 + wm * 64 + mt * 16 + quad * 4;
#pragma unroll
        for (int nt = 0; nt < 4; ++nt) {
            int col = wn * 64 + nt * 16 + l15;
            float bv = bias ? bias[col] : 0.0f;
#pragma unroll
            for (int r = 0; r < 4; ++r) {
                int m = mbase + r;
                if (m < M) {
                    float v = acc[mt][nt][r] + bv;
                    if (addin) v += addin[(size_t)m * BN + col];
                    if (relu) v = fmaxf(v, 0.f);
                    if constexpr (OUT_BF16) {
                        __hip_bfloat16 h = __float2bfloat16(v);
                        ((unsigned short*)Cout)[(size_t)m * BN + col] = *(unsigned short*)&h;
                    } else {
                        ((float*)Cout)[(size_t)m * BN + col] = v;
                    }
                }
            }
        }
    }
}

// ---------------- launch ----------------

static inline size_t align_up(size_t x) { return (x + 255) & ~(size_t)255; }

extern "C" void kernel_launch(void* const* d_in, const int* in_sizes, int n_in,
                              void* d_out, int out_size, void* d_ws, size_t ws_size,
                              hipStream_t stream) {
    const float* x   = (const float*)d_in[0];
    const int*   src = (const int*)d_in[1];
    const int*   dst = (const int*)d_in[2];
    const float* Ws0 = (const float*)d_in[3];
    const float* Wn0 = (const float*)d_in[4];
    const float* b0  = (const float*)d_in[5];
    const float* Ws1 = (const float*)d_in[6];
    const float* Wn1 = (const float*)d_in[7];
    const float* b1  = (const float*)d_in[8];
    const float* Ws2 = (const float*)d_in[9];
    const float* Wn2 = (const float*)d_in[10];
    const float* b2  = (const float*)d_in[11];
    float* out = (float*)d_out;

    const int NN = in_sizes[0] / NFEAT;   // 50000
    const int E  = in_sizes[1];           // 800000

    char* w = (char*)d_ws;
    ushort* X16  = (ushort*)w; w += align_up((size_t)NN * NFEAT * 2);
    ushort* Ha   = (ushort*)w; w += align_up((size_t)NN * NFEAT * 2);
    ushort* Hb   = (ushort*)w; w += align_up((size_t)NN * NFEAT * 2);
    ushort* AGG  = (ushort*)w; w += align_up((size_t)NN * NFEAT * 2);
    ushort* Wt0  = (ushort*)w; w += align_up((size_t)128 * 256 * 2);
    ushort* Wt1  = (ushort*)w; w += align_up((size_t)128 * 256 * 2);
    ushort* Wt2  = (ushort*)w; w += align_up((size_t)64 * 256 * 2);
    int* ptrA    = (int*)w;    w += align_up((size_t)(NN + 1) * 4);
    int* deg4    = (int*)w;    w += align_up((size_t)4 * NN * 4);
    int* off1    = (int*)w;    w += align_up((size_t)NN * 4);
    int* off2    = (int*)w;    w += align_up((size_t)NN * 4);
    int* off3    = (int*)w;    w += align_up((size_t)NN * 4);
    int* parts   = (int*)w;    w += align_up(256 * 4);
    int* csr     = (int*)w;    w += align_up((size_t)E * 4);

    // aliased scratch (lifetimes disjoint):
    int*    rnk = (int*)Ha;      // CSR build only, before Ha written
    ushort* G2  = X16;           // layer-2 projected table, after X16 dead
    float*  A2  = (float*)AGG;   // layer-2 fp32 aggregate, after AGG dead

    hipMemsetAsync(deg4, 0, (size_t)4 * NN * 4, stream);

    const int e4b = (E / 4 + 255) / 256;
    const int nb  = (NN + 255) / 256;    // 196 <= 256: single-block scan2 ok

    k_count<<<e4b, 256, 0, stream>>>(dst, deg4, rnk, E, NN);
    k_scan1<<<nb, 256, 0, stream>>>(deg4, off1, off2, off3, ptrA, parts, NN);
    k_scan2<<<1, 256, 0, stream>>>(parts, nb);
    k_scan3<<<nb, 256, 0, stream>>>(ptrA, parts, NN, E);
    k_scatter<<<e4b, 256, 0, stream>>>(src, dst, rnk, ptrA, off1, off2, off3, csr, E);

    const int n2 = NN * NFEAT / 2;
    k_cvt_bf16<<<(n2 + 255) / 256, 256, 0, stream>>>(x, X16, n2);
    k_wprep<<<(128 * 256 + 255) / 256, 256, 0, stream>>>(Ws0, Wn0, Wt0, 128);
    k_wprep<<<(128 * 256 + 255) / 256, 256, 0, stream>>>(Ws1, Wn1, Wt1, 128);
    k_wprep<<<(64 * 256 + 255) / 256, 256, 0, stream>>>(Ws2, Wn2, Wt2, 64);

    const int ab = (NN * 64 + 255) / 256;
    const int gm = (NN + 127) / 128;

    // layer 0: X16 -> Ha (ReLU)
    k_agg_t<128, true><<<ab, 256, 0, stream>>>(X16, ptrA, csr, AGG, NN);
    gemm_mfma<128, 8, true, true><<<gm, 256, 0, stream>>>(X16, AGG, Wt0, 256, b0, nullptr, Ha, NN, 1);

    // layer 1: Ha -> Hb (ReLU)
    k_agg_t<128, true><<<ab, 256, 0, stream>>>(Ha, ptrA, csr, AGG, NN);
    gemm_mfma<128, 8, true, true><<<gm, 256, 0, stream>>>(Ha, AGG, Wt1, 256, b1, nullptr, Hb, NN, 1);

    // layer 2: agg(Hb)@Wn2 == agg(Hb@Wn2) -> 64-wide gather table
    gemm_mfma<64, 4, false, true><<<gm, 128, 0, stream>>>(Hb, nullptr, Wt2 + 128, 256, nullptr, nullptr, G2, NN, 0);
    k_agg_t<64, false><<<ab, 256, 0, stream>>>(G2, ptrA, csr, A2, NN);
    gemm_mfma<64, 4, false, false><<<gm, 128, 0, stream>>>(Hb, nullptr, Wt2, 256, b2, A2, out, NN, 0);
}